// Round 10
// baseline (304.463 us; speedup 1.0000x reference)
//
#include <hip/hip_runtime.h>
#include <hip/hip_bf16.h>

// Problem constants (from reference):
#define NN 50000   // nodes
#define FF 128     // in channels
#define NH 4       // heads
#define CH 32      // channels/head
#define HC 128     // NH*CH
#define NE 800000  // edges
#define NR 8       // relations
#define DEDIM 64   // edge emb dim
#define NBLK 196   // ceil(NN/256)
#define HBLK 3125  // NE/256
#define QBLK 250   // M-chunk blocks per group in qkvs
#define MTILES 3125 // NN/16

typedef __hip_bfloat16 bf16;
typedef __attribute__((ext_vector_type(8))) short short8;   // 8 x bf16 (4 VGPR)
typedef __attribute__((ext_vector_type(4))) float f32x4;

// ---- helpers ----------------------------------------------------------------
__device__ __forceinline__ float bflo(unsigned u) { return __uint_as_float(u << 16); }
__device__ __forceinline__ float bfhi(unsigned u) { return __uint_as_float(u & 0xFFFF0000u); }

__device__ __forceinline__ unsigned short f2bf(float f) {
  unsigned u = __float_as_uint(f);
  unsigned r = (u + 0x7FFFu + ((u >> 16) & 1u)) >> 16;  // round-nearest-even
  return (unsigned short)r;
}
__device__ __forceinline__ unsigned pack2bf(float lo, float hi) {
  return (unsigned)f2bf(lo) | ((unsigned)f2bf(hi) << 16);
}

template <int ISBF>
__device__ __forceinline__ float ldf(const void* p, size_t i) {
  if (ISBF) return __bfloat162float(((const bf16*)p)[i]);
  return ((const float*)p)[i];
}

__device__ __forceinline__ int idx_at(const void* p, long long i, int is64) {
  if (is64) { long long v = ((const long long*)p)[i]; return (int)v; }
  return ((const int*)p)[i];
}

// ---- edge prep: hist + packed dst/srcet side arrays (self-detect is64) ------
// No LDS, low VGPR -> high occupancy (this was the round-9 regression).
__global__ __launch_bounds__(256) void k_prep(const int* __restrict__ eidx32,
    const void* __restrict__ etype, int* __restrict__ hist,
    int* __restrict__ dstp, int* __restrict__ setp) {
  // wave-local int64 detection: 64 distinct hi-word samples
  unsigned long long b = __ballot(eidx32[2 * (threadIdx.x & 63) + 1] != 0);
  int is64 = (b == 0ULL);
  int e = blockIdx.x * 256 + threadIdx.x;   // always < NE (HBLK*256 == NE)
  int src = idx_at(eidx32, e, is64);
  int dst = idx_at(eidx32, (long long)NE + e, is64);
  int et  = idx_at(etype, e, is64);
  src = min(max(src, 0), NN - 1);
  dst = min(max(dst, 0), NN - 1);
  et  = min(max(et, 0), NR - 1);
  dstp[e] = dst;
  setp[e] = (src << 3) | et;
  atomicAdd(&hist[dst], 1);
}

// ---- MFMA projection pieces --------------------------------------------------
#define WT_STRIDE 136   // bf16 elems; 272 B rows: 16B-aligned, 2-way max bank alias

template <int ISBF>
__device__ __forceinline__ void stage_w(const void* __restrict__ W,
                                        unsigned short* __restrict__ wt) {
  for (int i = threadIdx.x; i < FF * HC; i += 256) {
    int k = i >> 7, n = i & 127;
    wt[n * WT_STRIDE + k] = ISBF ? ((const unsigned short*)W)[i]
                                 : f2bf(((const float*)W)[i]);
  }
}

__device__ __forceinline__ void hoist_b(const unsigned short* __restrict__ wt,
                                        int wv, int quad, int lr,
                                        short8 bf[2][4]) {
#pragma unroll
  for (int t = 0; t < 2; ++t) {
    int ncol = wv * 32 + t * 16 + lr;
#pragma unroll
    for (int kb = 0; kb < 4; ++kb)
      bf[t][kb] = *(const short8*)&wt[ncol * WT_STRIDE + kb * 32 + quad * 8];
  }
}

template <int ISBF>
__device__ __forceinline__ void load_a(const void* __restrict__ x, int m0,
                                       int lr, int quad, short8 af[4]) {
  const unsigned short* xu = (const unsigned short*)x;
  const float* xf = (const float*)x;
#pragma unroll
  for (int kb = 0; kb < 4; ++kb) {
    size_t off = (size_t)(m0 + lr) * FF + kb * 32 + quad * 8;
    if (ISBF) {
      af[kb] = *(const short8*)(xu + off);
    } else {
      float4 fa = *(const float4*)(xf + off);
      float4 fb = *(const float4*)(xf + off + 4);
      short8 a;
      a[0] = (short)f2bf(fa.x); a[1] = (short)f2bf(fa.y);
      a[2] = (short)f2bf(fa.z); a[3] = (short)f2bf(fa.w);
      a[4] = (short)f2bf(fb.x); a[5] = (short)f2bf(fb.y);
      a[6] = (short)f2bf(fb.z); a[7] = (short)f2bf(fb.w);
      af[kb] = a;
    }
  }
}

template <int ISBF>
__device__ __forceinline__ void qkvs_body(const void* __restrict__ x,
    const void* __restrict__ W0, const void* __restrict__ W1, int grp, int mc,
    unsigned short* __restrict__ qb, unsigned* __restrict__ kvb,
    void* __restrict__ out, unsigned short* wt) {
  const int lane = threadIdx.x & 63;
  const int wv   = threadIdx.x >> 6;
  const int quad = lane >> 4;
  const int lr   = lane & 15;
  short8 bf0[2][4], bf1[2][4];
  stage_w<ISBF>(W0, wt);
  __syncthreads();
  hoist_b(wt, wv, quad, lr, bf0);
  __syncthreads();           // all reads of W0 done before overwrite
  stage_w<ISBF>(W1, wt);
  __syncthreads();
  hoist_b(wt, wv, quad, lr, bf1);
  // software pipeline: prefetch next tile's A while current tile MFMAs run
  short8 af[4], nf[4];
  load_a<ISBF>(x, mc * 16, lr, quad, af);
  for (int mt = mc; mt < MTILES; mt += QBLK) {
    int m0 = mt * 16;
    int nmt = mt + QBLK;
    int pm0 = (nmt < MTILES ? nmt : mt) * 16;   // clamp: always issue loads
    load_a<ISBF>(x, pm0, lr, quad, nf);
    f32x4 a00 = {0.f, 0.f, 0.f, 0.f}, a01 = {0.f, 0.f, 0.f, 0.f};
    f32x4 a10 = {0.f, 0.f, 0.f, 0.f}, a11 = {0.f, 0.f, 0.f, 0.f};
#pragma unroll
    for (int kb = 0; kb < 4; ++kb) {
      a00 = __builtin_amdgcn_mfma_f32_16x16x32_bf16(af[kb], bf0[0][kb], a00, 0, 0, 0);
      a01 = __builtin_amdgcn_mfma_f32_16x16x32_bf16(af[kb], bf0[1][kb], a01, 0, 0, 0);
      a10 = __builtin_amdgcn_mfma_f32_16x16x32_bf16(af[kb], bf1[0][kb], a10, 0, 0, 0);
      a11 = __builtin_amdgcn_mfma_f32_16x16x32_bf16(af[kb], bf1[1][kb], a11, 0, 0, 0);
    }
#pragma unroll
    for (int t = 0; t < 2; ++t) {
      const f32x4 v0 = t ? a01 : a00;   // mat0: q or k
      const f32x4 v1 = t ? a11 : a10;   // mat1: skip or v
      int col = wv * 32 + t * 16 + lr;
#pragma unroll
      for (int r = 0; r < 4; ++r) {
        size_t oi = (size_t)(m0 + quad * 4 + r) * HC + col;
        if (grp == 0) {
          qb[oi] = f2bf(v0[r]);
          if (ISBF) ((unsigned short*)out)[oi] = f2bf(v1[r]);
          else      ((float*)out)[oi] = v1[r];
        } else {
          kvb[oi] = pack2bf(v0[r], v1[r]);   // k low16, v high16
        }
      }
    }
#pragma unroll
    for (int kb = 0; kb < 4; ++kb) af[kb] = nf[kb];
  }
}

// blocks [0, 2*QBLK): MFMA projections (self-detect bf16); last block: flags+ee
__global__ __launch_bounds__(256) void k_qkvs(const unsigned* __restrict__ xw,
    const int* __restrict__ eidx32, const void* __restrict__ emb,
    const void* __restrict__ We, const void* __restrict__ Wq,
    const void* __restrict__ Wk, const void* __restrict__ Wv,
    const void* __restrict__ Ws, int* __restrict__ flag,
    float* __restrict__ ee, unsigned short* __restrict__ qb,
    unsigned* __restrict__ kvb, void* __restrict__ out) {
  __shared__ unsigned short wt[HC * WT_STRIDE];   // ~34 KB (aliased below)
  if (blockIdx.x < 2 * QBLK) {
    // wave-local bf16 detection: 64 exponent samples of x's low halves
    unsigned ex = (xw[threadIdx.x & 63] >> 7) & 0xFFu;
    unsigned long long bb = __ballot(ex < 90u || ex > 140u);
    int isbf = (bb == 0ULL);
    int grp = blockIdx.x / QBLK;   // 0: q+skip, 1: k+v
    int mc  = blockIdx.x % QBLK;
    const void* W0 = grp ? Wk : Wq;
    const void* W1 = grp ? Wv : Ws;
    if (isbf) qkvs_body<1>(xw, W0, W1, grp, mc, qb, kvb, out, wt);
    else      qkvs_body<0>(xw, W0, W1, grp, mc, qb, kvb, out, wt);
    return;
  }
  // last block: flags + ee
  float* es = (float*)wt;   // alias (this block doesn't run qkvs)
  __shared__ int nzIdx, badBf;
  if (threadIdx.x == 0) { nzIdx = 0; badBf = 0; }
  __syncthreads();
  if (threadIdx.x < 128) {
    if (eidx32[2 * threadIdx.x + 1] != 0) atomicAdd(&nzIdx, 1);
    unsigned e = (xw[threadIdx.x] >> 7) & 0xFFu;
    if (e < 90u || e > 140u) atomicAdd(&badBf, 1);
  }
  __syncthreads();
  const int isbf = (badBf == 0);
  if (threadIdx.x == 0) { flag[0] = (nzIdx == 0); flag[1] = isbf; }
  for (int i = threadIdx.x; i < NR * DEDIM; i += 256)
    es[i] = isbf ? ldf<1>(emb, i) : ldf<0>(emb, i);
  __syncthreads();
  for (int o = threadIdx.x; o < NR * HC; o += 256) {
    int r = o >> 7, j = o & 127;
    float acc = 0.f;
    if (isbf) { for (int d = 0; d < DEDIM; ++d) acc += es[r * DEDIM + d] * ldf<1>(We, d * HC + j); }
    else      { for (int d = 0; d < DEDIM; ++d) acc += es[r * DEDIM + d] * ldf<0>(We, d * HC + j); }
    ee[o] = acc;
  }
}

// ---- scan: block sums (scan1), then per-block scan with inline top scan ------
__global__ __launch_bounds__(256) void k_scan1(const int* __restrict__ hist,
                                               int* __restrict__ bsum) {
  __shared__ int red[4];
  int i = blockIdx.x * 256 + threadIdx.x;
  int v = (i < NN) ? hist[i] : 0;
#pragma unroll
  for (int m = 1; m < 64; m <<= 1) v += __shfl_xor(v, m);
  if ((threadIdx.x & 63) == 0) red[threadIdx.x >> 6] = v;
  __syncthreads();
  if (threadIdx.x == 0) bsum[blockIdx.x] = red[0] + red[1] + red[2] + red[3];
}

__global__ __launch_bounds__(256) void k_scan13(const int* __restrict__ hist,
    const int* __restrict__ bsum, int* __restrict__ rowptr,
    int* __restrict__ cursor) {
  __shared__ int s[256];
  int t = threadIdx.x;
  int bv = (t < NBLK) ? bsum[t] : 0;
  s[t] = bv;
  __syncthreads();
  for (int off = 1; off < 256; off <<= 1) {
    int u = (t >= off) ? s[t - off] : 0;
    __syncthreads();
    s[t] += u;
    __syncthreads();
  }
  int bexc = (blockIdx.x == 0) ? 0 : s[blockIdx.x - 1];  // uniform
  __syncthreads();
  int i = blockIdx.x * 256 + t;
  int v = (i < NN) ? hist[i] : 0;
  s[t] = v;
  __syncthreads();
  for (int off = 1; off < 256; off <<= 1) {
    int u = (t >= off) ? s[t - off] : 0;
    __syncthreads();
    s[t] += u;
    __syncthreads();
  }
  int excl = bexc + s[t] - v;
  if (i < NN) { rowptr[i] = excl; cursor[i] = excl; }  // cursor aliases hist: block-local RAW, safe
  if (i == 0) rowptr[NN] = NE;   // all edges binned (dst clamped)
}

// scatter pre-packed (src<<3 | et) into dst-sorted order (int32 side arrays)
__global__ __launch_bounds__(256) void k_scatter(const int* __restrict__ dstp,
    const int* __restrict__ setp, int* __restrict__ cursor,
    int* __restrict__ srcet) {
  int e = blockIdx.x * 256 + threadIdx.x;   // HBLK*256 == NE
  int dst = dstp[e];
  int pos = atomicAdd(&cursor[dst], 1);
  srcet[pos] = setp[e];
}

// ---- fused attention+gather: half-wave per edge, 4 channels/lane ------------
// lane l: t = l>>5 (edge slot), w = l&31, head = w>>3, j0 = 32*head + 4*(w&7)
__global__ __launch_bounds__(256) void k_gather(const int* __restrict__ rowptr,
    const int* __restrict__ srcet, const unsigned short* __restrict__ qb,
    const unsigned* __restrict__ kvb, const float* __restrict__ ee,
    const int* __restrict__ flag, void* __restrict__ out) {
  int n = blockIdx.x * 4 + (threadIdx.x >> 6);   // wave-uniform node
  int l = threadIdx.x & 63;
  int t = l >> 5;
  int w = l & 31;
  int j0 = ((w >> 3) << 5) + ((w & 7) << 2);     // 4-channel base
  int beg = __builtin_amdgcn_readfirstlane(rowptr[n]);
  int end = __builtin_amdgcn_readfirstlane(rowptr[n + 1]);
  uint2 qw = *(const uint2*)(qb + (size_t)n * HC + j0);
  float q0 = bflo(qw.x), q1 = bfhi(qw.x), q2 = bflo(qw.y), q3 = bfhi(qw.y);
  const float sc = 0.17677669529663687f;  // 1/sqrt(32)
  float dn = 0.f, a0 = 0.f, a1 = 0.f, a2 = 0.f, a3 = 0.f;
  int p = beg;
  // main: 4 pairs (8 edges) per iteration, unmasked
  for (; p + 8 <= end; p += 8) {
    int se[4]; uint4 kv[4]; float4 ev[4];
#pragma unroll
    for (int u = 0; u < 4; ++u) se[u] = srcet[p + 2 * u + t];
#pragma unroll
    for (int u = 0; u < 4; ++u)
      kv[u] = *(const uint4*)(kvb + (size_t)(se[u] >> 3) * HC + j0);
#pragma unroll
    for (int u = 0; u < 4; ++u)
      ev[u] = *(const float4*)(ee + ((se[u] & 7) << 7) + j0);
#pragma unroll
    for (int u = 0; u < 4; ++u) {
      float pp = q0 * (bflo(kv[u].x) + ev[u].x) + q1 * (bflo(kv[u].y) + ev[u].y)
               + q2 * (bflo(kv[u].z) + ev[u].z) + q3 * (bflo(kv[u].w) + ev[u].w);
      pp += __shfl_xor(pp, 1);
      pp += __shfl_xor(pp, 2);
      pp += __shfl_xor(pp, 4);
      float xx = __expf(pp * sc);
      dn += xx;
      a0 += (bfhi(kv[u].x) + ev[u].x) * xx;
      a1 += (bfhi(kv[u].y) + ev[u].y) * xx;
      a2 += (bfhi(kv[u].z) + ev[u].z) * xx;
      a3 += (bfhi(kv[u].w) + ev[u].w) * xx;
    }
  }
  // epilogue: one masked 4-pair iteration covers the <8 remaining edges
  if (p < end) {
    int se[4]; bool ok[4]; uint4 kv[4]; float4 ev[4];
#pragma unroll
    for (int u = 0; u < 4; ++u) {
      int pe = p + 2 * u + t;
      ok[u] = pe < end;
      se[u] = srcet[ok[u] ? pe : beg];
    }
#pragma unroll
    for (int u = 0; u < 4; ++u)
      kv[u] = *(const uint4*)(kvb + (size_t)(se[u] >> 3) * HC + j0);
#pragma unroll
    for (int u = 0; u < 4; ++u)
      ev[u] = *(const float4*)(ee + ((se[u] & 7) << 7) + j0);
#pragma unroll
    for (int u = 0; u < 4; ++u) {
      float pp = q0 * (bflo(kv[u].x) + ev[u].x) + q1 * (bflo(kv[u].y) + ev[u].y)
               + q2 * (bflo(kv[u].z) + ev[u].z) + q3 * (bflo(kv[u].w) + ev[u].w);
      pp += __shfl_xor(pp, 1);
      pp += __shfl_xor(pp, 2);
      pp += __shfl_xor(pp, 4);
      float xx = ok[u] ? __expf(pp * sc) : 0.f;
      dn += xx;
      a0 += (bfhi(kv[u].x) + ev[u].x) * xx;
      a1 += (bfhi(kv[u].y) + ev[u].y) * xx;
      a2 += (bfhi(kv[u].z) + ev[u].z) * xx;
      a3 += (bfhi(kv[u].w) + ev[u].w) * xx;
    }
  }
  // combine the two half-waves (linear in numerator and denominator)
  dn += __shfl_xor(dn, 32);
  a0 += __shfl_xor(a0, 32);
  a1 += __shfl_xor(a1, 32);
  a2 += __shfl_xor(a2, 32);
  a3 += __shfl_xor(a3, 32);
  if (t == 0) {
    float inv = 1.f / (dn + 1e-16f);
    size_t oi = (size_t)n * HC + j0;
    if (flag[1]) {  // skip pre-stored dtype-matched in d_out; same-thread RAW, safe
      uint2 sk = *(const uint2*)((const unsigned short*)out + oi);
      uint2 o;
      o.x = pack2bf(a0 * inv + bflo(sk.x), a1 * inv + bfhi(sk.x));
      o.y = pack2bf(a2 * inv + bflo(sk.y), a3 * inv + bfhi(sk.y));
      *(uint2*)((unsigned short*)out + oi) = o;
    } else {
      float4 sk = *(const float4*)((const float*)out + oi);
      float4 o = make_float4(a0 * inv + sk.x, a1 * inv + sk.y,
                             a2 * inv + sk.z, a3 * inv + sk.w);
      *(float4*)((float*)out + oi) = o;
    }
  }
}

// ---- launch -----------------------------------------------------------------
extern "C" void kernel_launch(void* const* d_in, const int* in_sizes, int n_in,
                              void* d_out, int out_size, void* d_ws, size_t ws_size,
                              hipStream_t stream) {
  const void* x     = d_in[0];
  const void* eidx  = d_in[1];   // [2,E]: first E = src, next E = dst
  const void* etype = d_in[2];
  const void* emb   = d_in[3];
  const void* Wq    = d_in[4];
  const void* Wk    = d_in[5];
  const void* Wv    = d_in[6];
  const void* We    = d_in[7];
  const void* Ws    = d_in[8];

  // workspace layout (float units) — total ~48.4 MB (round-3/4 proven-safe)
  float* base   = (float*)d_ws;
  int*   flag   = (int*)base;                       // 16
  float* ee     = base + 16;                        // 1024 -> 1040
  int*   rowptr = (int*)(base + 1040);              // 50001 -> pad 50004
  int*   cursor = (int*)(base + 51044);             // 50000 (doubles as hist)
  int*   bsum   = (int*)(base + 101044);            // 196 -> pad 524
  int*   srcet  = (int*)(base + 101568);            // NE -> 901568
  int*   dstp   = (int*)(base + 901568);            // NE -> 1701568
  int*   setp   = (int*)(base + 1701568);           // NE -> 2501568
  unsigned short* qb  = (unsigned short*)(base + 2501568);  // NN*HC bf16 (3.2M fl)
  unsigned*       kvb = (unsigned*)(base + 5701568);        // NN*HC uint (6.4M fl)
  // end: 12101568 floats = 48.41 MB

  hipMemsetAsync(cursor, 0, NN * sizeof(int), stream);   // hist zero (capture-safe)
  k_prep   <<<HBLK, 256, 0, stream>>>((const int*)eidx, etype, cursor, dstp, setp);
  k_qkvs   <<<2 * QBLK + 1, 256, 0, stream>>>((const unsigned*)x, (const int*)eidx,
                                          emb, We, Wq, Wk, Wv, Ws,
                                          flag, ee, qb, kvb, d_out);
  k_scan1  <<<NBLK, 256, 0, stream>>>(cursor, bsum);
  k_scan13 <<<NBLK, 256, 0, stream>>>(cursor, bsum, rowptr, cursor);
  k_scatter<<<HBLK, 256, 0, stream>>>(dstp, setp, cursor, srcet);
  k_gather <<<NN / 4, 256, 0, stream>>>(rowptr, srcet, qb, kvb, ee, flag, d_out);
}

// Round 12
// 261.433 us; speedup vs baseline: 1.1646x; 1.1646x over previous
//
#include <hip/hip_runtime.h>
#include <hip/hip_bf16.h>

// Problem constants (from reference):
#define NN 50000   // nodes
#define FF 128     // in channels
#define NH 4       // heads
#define CH 32      // channels/head
#define HC 128     // NH*CH
#define NE 800000  // edges
#define NR 8       // relations
#define DEDIM 64   // edge emb dim
#define NBLK 196   // ceil(NN/256)
#define HBLK 3125  // NE/256
#define QBLK 250   // M-chunk blocks per group in qkvs
#define MTILES 3125 // NN/16

typedef __hip_bfloat16 bf16;
typedef __attribute__((ext_vector_type(8))) short short8;   // 8 x bf16 (4 VGPR)
typedef __attribute__((ext_vector_type(4))) float f32x4;

// ---- helpers ----------------------------------------------------------------
__device__ __forceinline__ float bflo(unsigned u) { return __uint_as_float(u << 16); }
__device__ __forceinline__ float bfhi(unsigned u) { return __uint_as_float(u & 0xFFFF0000u); }

__device__ __forceinline__ unsigned short f2bf(float f) {
  unsigned u = __float_as_uint(f);
  unsigned r = (u + 0x7FFFu + ((u >> 16) & 1u)) >> 16;  // round-nearest-even
  return (unsigned short)r;
}
__device__ __forceinline__ unsigned pack2bf(float lo, float hi) {
  return (unsigned)f2bf(lo) | ((unsigned)f2bf(hi) << 16);
}

template <int ISBF>
__device__ __forceinline__ float ldf(const void* p, size_t i) {
  if (ISBF) return __bfloat162float(((const bf16*)p)[i]);
  return ((const float*)p)[i];
}

__device__ __forceinline__ int idx_at(const void* p, long long i, int is64) {
  if (is64) { long long v = ((const long long*)p)[i]; return (int)v; }
  return ((const int*)p)[i];
}

// ---- edge prep (lean): hist + dst/srcet side arrays; last block: flags+ee ---
// hist pre-zeroed via hipMemsetAsync. LDS only 2KB -> high occupancy.
__global__ __launch_bounds__(256) void k_prep(const int* __restrict__ eidx32,
    const void* __restrict__ etype, const unsigned* __restrict__ xw,
    const void* __restrict__ emb, const void* __restrict__ We,
    int* __restrict__ flag, int* __restrict__ hist, float* __restrict__ ee,
    int* __restrict__ dstp, int* __restrict__ setp) {
  __shared__ float es[NR * DEDIM];   // 2 KB (last block only)
  if (blockIdx.x < HBLK) {
    // wave-local int64 detection: 64 distinct hi-word samples
    unsigned long long b = __ballot(eidx32[2 * (threadIdx.x & 63) + 1] != 0);
    int is64 = (b == 0ULL);
    int e = blockIdx.x * 256 + threadIdx.x;   // always < NE (HBLK*256 == NE)
    int src = idx_at(eidx32, e, is64);
    int dst = idx_at(eidx32, (long long)NE + e, is64);
    int et  = idx_at(etype, e, is64);
    src = min(max(src, 0), NN - 1);
    dst = min(max(dst, 0), NN - 1);
    et  = min(max(et, 0), NR - 1);
    dstp[e] = dst;
    setp[e] = (src << 3) | et;
    atomicAdd(&hist[dst], 1);
    return;
  }
  // last block: flags + ee
  __shared__ int nzIdx, badBf;
  if (threadIdx.x == 0) { nzIdx = 0; badBf = 0; }
  __syncthreads();
  if (threadIdx.x < 128) {
    if (eidx32[2 * threadIdx.x + 1] != 0) atomicAdd(&nzIdx, 1);
    unsigned e = (xw[threadIdx.x] >> 7) & 0xFFu;  // exponent of low-half bf16
    if (e < 90u || e > 140u) atomicAdd(&badBf, 1);
  }
  __syncthreads();
  const int isbf = (badBf == 0);
  if (threadIdx.x == 0) { flag[0] = (nzIdx == 0); flag[1] = isbf; }
  for (int i = threadIdx.x; i < NR * DEDIM; i += 256)
    es[i] = isbf ? ldf<1>(emb, i) : ldf<0>(emb, i);
  __syncthreads();
  for (int o = threadIdx.x; o < NR * HC; o += 256) {
    int r = o >> 7, j = o & 127;
    float acc = 0.f;
    if (isbf) { for (int d = 0; d < DEDIM; ++d) acc += es[r * DEDIM + d] * ldf<1>(We, d * HC + j); }
    else      { for (int d = 0; d < DEDIM; ++d) acc += es[r * DEDIM + d] * ldf<0>(We, d * HC + j); }
    ee[o] = acc;
  }
}

// ---- scan: block sums (scan1), then per-block scan with inline top scan ------
__global__ __launch_bounds__(256) void k_scan1(const int* __restrict__ hist,
                                               int* __restrict__ bsum) {
  __shared__ int red[4];
  int i = blockIdx.x * 256 + threadIdx.x;
  int v = (i < NN) ? hist[i] : 0;
#pragma unroll
  for (int m = 1; m < 64; m <<= 1) v += __shfl_xor(v, m);
  if ((threadIdx.x & 63) == 0) red[threadIdx.x >> 6] = v;
  __syncthreads();
  if (threadIdx.x == 0) bsum[blockIdx.x] = red[0] + red[1] + red[2] + red[3];
}

__global__ __launch_bounds__(256) void k_scan13(const int* __restrict__ hist,
    const int* __restrict__ bsum, int* __restrict__ rowptr,
    int* __restrict__ cursor) {
  __shared__ int s[256];
  int t = threadIdx.x;
  int bv = (t < NBLK) ? bsum[t] : 0;
  s[t] = bv;
  __syncthreads();
  for (int off = 1; off < 256; off <<= 1) {
    int u = (t >= off) ? s[t - off] : 0;
    __syncthreads();
    s[t] += u;
    __syncthreads();
  }
  int bexc = (blockIdx.x == 0) ? 0 : s[blockIdx.x - 1];  // uniform
  __syncthreads();
  int i = blockIdx.x * 256 + t;
  int v = (i < NN) ? hist[i] : 0;
  s[t] = v;
  __syncthreads();
  for (int off = 1; off < 256; off <<= 1) {
    int u = (t >= off) ? s[t - off] : 0;
    __syncthreads();
    s[t] += u;
    __syncthreads();
  }
  int excl = bexc + s[t] - v;
  if (i < NN) { rowptr[i] = excl; cursor[i] = excl; }  // cursor aliases hist: block-local RAW, safe
  if (i == 0) rowptr[NN] = NE;   // all edges binned (dst clamped)
}

// ---- MFMA projection pieces (round-8 form: no prefetch pipeline) ------------
#define WT_STRIDE 136   // bf16 elems; 272 B rows: 16B-aligned, 2-way max bank alias

template <int ISBF>
__device__ __forceinline__ void stage_w(const void* __restrict__ W,
                                        unsigned short* __restrict__ wt) {
  for (int i = threadIdx.x; i < FF * HC; i += 256) {
    int k = i >> 7, n = i & 127;
    wt[n * WT_STRIDE + k] = ISBF ? ((const unsigned short*)W)[i]
                                 : f2bf(((const float*)W)[i]);
  }
}

__device__ __forceinline__ void hoist_b(const unsigned short* __restrict__ wt,
                                        int wv, int quad, int lr,
                                        short8 bf[2][4]) {
#pragma unroll
  for (int t = 0; t < 2; ++t) {
    int ncol = wv * 32 + t * 16 + lr;
#pragma unroll
    for (int kb = 0; kb < 4; ++kb)
      bf[t][kb] = *(const short8*)&wt[ncol * WT_STRIDE + kb * 32 + quad * 8];
  }
}

template <int ISBF>
__device__ __forceinline__ void qkvs_body(const void* __restrict__ x,
    const void* __restrict__ W0, const void* __restrict__ W1, int grp, int mc,
    unsigned short* __restrict__ qb, unsigned* __restrict__ kvb,
    void* __restrict__ out, unsigned short* wt) {
  const int lane = threadIdx.x & 63;
  const int wv   = threadIdx.x >> 6;
  const int quad = lane >> 4;
  const int lr   = lane & 15;
  short8 bf0[2][4], bf1[2][4];
  stage_w<ISBF>(W0, wt);
  __syncthreads();
  hoist_b(wt, wv, quad, lr, bf0);
  __syncthreads();           // all reads of W0 done before overwrite
  stage_w<ISBF>(W1, wt);
  __syncthreads();
  hoist_b(wt, wv, quad, lr, bf1);
  const unsigned short* xu = (const unsigned short*)x;
  const float* xf = (const float*)x;
  for (int mt = mc; mt < MTILES; mt += QBLK) {
    int m0 = mt * 16;
    short8 af[4];
#pragma unroll
    for (int kb = 0; kb < 4; ++kb) {
      size_t off = (size_t)(m0 + lr) * FF + kb * 32 + quad * 8;
      if (ISBF) {
        af[kb] = *(const short8*)(xu + off);
      } else {
        float4 fa = *(const float4*)(xf + off);
        float4 fb = *(const float4*)(xf + off + 4);
        short8 a;
        a[0] = (short)f2bf(fa.x); a[1] = (short)f2bf(fa.y);
        a[2] = (short)f2bf(fa.z); a[3] = (short)f2bf(fa.w);
        a[4] = (short)f2bf(fb.x); a[5] = (short)f2bf(fb.y);
        a[6] = (short)f2bf(fb.z); a[7] = (short)f2bf(fb.w);
        af[kb] = a;
      }
    }
    f32x4 a00 = {0.f, 0.f, 0.f, 0.f}, a01 = {0.f, 0.f, 0.f, 0.f};
    f32x4 a10 = {0.f, 0.f, 0.f, 0.f}, a11 = {0.f, 0.f, 0.f, 0.f};
#pragma unroll
    for (int kb = 0; kb < 4; ++kb) {
      a00 = __builtin_amdgcn_mfma_f32_16x16x32_bf16(af[kb], bf0[0][kb], a00, 0, 0, 0);
      a01 = __builtin_amdgcn_mfma_f32_16x16x32_bf16(af[kb], bf0[1][kb], a01, 0, 0, 0);
      a10 = __builtin_amdgcn_mfma_f32_16x16x32_bf16(af[kb], bf1[0][kb], a10, 0, 0, 0);
      a11 = __builtin_amdgcn_mfma_f32_16x16x32_bf16(af[kb], bf1[1][kb], a11, 0, 0, 0);
    }
#pragma unroll
    for (int t = 0; t < 2; ++t) {
      const f32x4 v0 = t ? a01 : a00;   // mat0: q or k
      const f32x4 v1 = t ? a11 : a10;   // mat1: skip or v
      int col = wv * 32 + t * 16 + lr;
#pragma unroll
      for (int r = 0; r < 4; ++r) {
        size_t oi = (size_t)(m0 + quad * 4 + r) * HC + col;
        if (grp == 0) {
          qb[oi] = f2bf(v0[r]);
          if (ISBF) ((unsigned short*)out)[oi] = f2bf(v1[r]);
          else      ((float*)out)[oi] = v1[r];
        } else {
          kvb[oi] = pack2bf(v0[r], v1[r]);   // k low16, v high16
        }
      }
    }
  }
}

// ---- fused qkvs + scatter: overlap the MFMA pass with the sort's scatter ----
// blocks [0, 2*QBLK): qkvs (long-running, dispatched first);
// blocks [2*QBLK, 2*QBLK+HBLK): scatter (lean, backfills the CUs).
__global__ __launch_bounds__(256) void k_fused(const unsigned* __restrict__ xw,
    const void* __restrict__ Wq, const void* __restrict__ Wk,
    const void* __restrict__ Wv, const void* __restrict__ Ws,
    unsigned short* __restrict__ qb, unsigned* __restrict__ kvb,
    void* __restrict__ out,
    const int* __restrict__ dstp, const int* __restrict__ setp,
    int* __restrict__ cursor, int* __restrict__ srcet) {
  __shared__ unsigned short wt[HC * WT_STRIDE];   // ~34 KB (qkvs blocks only)
  if (blockIdx.x < 2 * QBLK) {
    // wave-local bf16 detection: 64 exponent samples of x's low halves
    unsigned ex = (xw[threadIdx.x & 63] >> 7) & 0xFFu;
    unsigned long long bb = __ballot(ex < 90u || ex > 140u);
    int isbf = (bb == 0ULL);
    int grp = blockIdx.x / QBLK;   // 0: q+skip, 1: k+v
    int mc  = blockIdx.x % QBLK;
    const void* W0 = grp ? Wk : Wq;
    const void* W1 = grp ? Wv : Ws;
    if (isbf) qkvs_body<1>(xw, W0, W1, grp, mc, qb, kvb, out, wt);
    else      qkvs_body<0>(xw, W0, W1, grp, mc, qb, kvb, out, wt);
    return;
  }
  // scatter: pre-packed (src<<3 | et) into dst-sorted order
  int e = (blockIdx.x - 2 * QBLK) * 256 + threadIdx.x;   // HBLK*256 == NE
  int dst = dstp[e];
  int pos = atomicAdd(&cursor[dst], 1);
  srcet[pos] = setp[e];
}

// ---- fused attention+gather: half-wave per edge, 4 channels/lane ------------
// lane l: t = l>>5 (edge slot), w = l&31, head = w>>3, j0 = 32*head + 4*(w&7)
__global__ __launch_bounds__(256) void k_gather(const int* __restrict__ rowptr,
    const int* __restrict__ srcet, const unsigned short* __restrict__ qb,
    const unsigned* __restrict__ kvb, const float* __restrict__ ee,
    const int* __restrict__ flag, void* __restrict__ out) {
  int n = blockIdx.x * 4 + (threadIdx.x >> 6);   // wave-uniform node
  int l = threadIdx.x & 63;
  int t = l >> 5;
  int w = l & 31;
  int j0 = ((w >> 3) << 5) + ((w & 7) << 2);     // 4-channel base
  int beg = __builtin_amdgcn_readfirstlane(rowptr[n]);
  int end = __builtin_amdgcn_readfirstlane(rowptr[n + 1]);
  uint2 qw = *(const uint2*)(qb + (size_t)n * HC + j0);
  float q0 = bflo(qw.x), q1 = bfhi(qw.x), q2 = bflo(qw.y), q3 = bfhi(qw.y);
  const float sc = 0.17677669529663687f;  // 1/sqrt(32)
  float dn = 0.f, a0 = 0.f, a1 = 0.f, a2 = 0.f, a3 = 0.f;
  int p = beg;
  // main: 4 pairs (8 edges) per iteration, unmasked
  for (; p + 8 <= end; p += 8) {
    int se[4]; uint4 kv[4]; float4 ev[4];
#pragma unroll
    for (int u = 0; u < 4; ++u) se[u] = srcet[p + 2 * u + t];
#pragma unroll
    for (int u = 0; u < 4; ++u)
      kv[u] = *(const uint4*)(kvb + (size_t)(se[u] >> 3) * HC + j0);
#pragma unroll
    for (int u = 0; u < 4; ++u)
      ev[u] = *(const float4*)(ee + ((se[u] & 7) << 7) + j0);
#pragma unroll
    for (int u = 0; u < 4; ++u) {
      float pp = q0 * (bflo(kv[u].x) + ev[u].x) + q1 * (bflo(kv[u].y) + ev[u].y)
               + q2 * (bflo(kv[u].z) + ev[u].z) + q3 * (bflo(kv[u].w) + ev[u].w);
      pp += __shfl_xor(pp, 1);
      pp += __shfl_xor(pp, 2);
      pp += __shfl_xor(pp, 4);
      float xx = __expf(pp * sc);
      dn += xx;
      a0 += (bfhi(kv[u].x) + ev[u].x) * xx;
      a1 += (bfhi(kv[u].y) + ev[u].y) * xx;
      a2 += (bfhi(kv[u].z) + ev[u].z) * xx;
      a3 += (bfhi(kv[u].w) + ev[u].w) * xx;
    }
  }
  // epilogue: one masked 4-pair iteration covers the <8 remaining edges
  if (p < end) {
    int se[4]; bool ok[4]; uint4 kv[4]; float4 ev[4];
#pragma unroll
    for (int u = 0; u < 4; ++u) {
      int pe = p + 2 * u + t;
      ok[u] = pe < end;
      se[u] = srcet[ok[u] ? pe : beg];
    }
#pragma unroll
    for (int u = 0; u < 4; ++u)
      kv[u] = *(const uint4*)(kvb + (size_t)(se[u] >> 3) * HC + j0);
#pragma unroll
    for (int u = 0; u < 4; ++u)
      ev[u] = *(const float4*)(ee + ((se[u] & 7) << 7) + j0);
#pragma unroll
    for (int u = 0; u < 4; ++u) {
      float pp = q0 * (bflo(kv[u].x) + ev[u].x) + q1 * (bflo(kv[u].y) + ev[u].y)
               + q2 * (bflo(kv[u].z) + ev[u].z) + q3 * (bflo(kv[u].w) + ev[u].w);
      pp += __shfl_xor(pp, 1);
      pp += __shfl_xor(pp, 2);
      pp += __shfl_xor(pp, 4);
      float xx = ok[u] ? __expf(pp * sc) : 0.f;
      dn += xx;
      a0 += (bfhi(kv[u].x) + ev[u].x) * xx;
      a1 += (bfhi(kv[u].y) + ev[u].y) * xx;
      a2 += (bfhi(kv[u].z) + ev[u].z) * xx;
      a3 += (bfhi(kv[u].w) + ev[u].w) * xx;
    }
  }
  // combine the two half-waves (linear in numerator and denominator)
  dn += __shfl_xor(dn, 32);
  a0 += __shfl_xor(a0, 32);
  a1 += __shfl_xor(a1, 32);
  a2 += __shfl_xor(a2, 32);
  a3 += __shfl_xor(a3, 32);
  if (t == 0) {
    float inv = 1.f / (dn + 1e-16f);
    size_t oi = (size_t)n * HC + j0;
    if (flag[1]) {  // skip pre-stored dtype-matched in d_out; same-thread RAW, safe
      uint2 sk = *(const uint2*)((const unsigned short*)out + oi);
      uint2 o;
      o.x = pack2bf(a0 * inv + bflo(sk.x), a1 * inv + bfhi(sk.x));
      o.y = pack2bf(a2 * inv + bflo(sk.y), a3 * inv + bfhi(sk.y));
      *(uint2*)((unsigned short*)out + oi) = o;
    } else {
      float4 sk = *(const float4*)((const float*)out + oi);
      float4 o = make_float4(a0 * inv + sk.x, a1 * inv + sk.y,
                             a2 * inv + sk.z, a3 * inv + sk.w);
      *(float4*)((float*)out + oi) = o;
    }
  }
}

// ---- launch -----------------------------------------------------------------
extern "C" void kernel_launch(void* const* d_in, const int* in_sizes, int n_in,
                              void* d_out, int out_size, void* d_ws, size_t ws_size,
                              hipStream_t stream) {
  const void* x     = d_in[0];
  const void* eidx  = d_in[1];   // [2,E]: first E = src, next E = dst
  const void* etype = d_in[2];
  const void* emb   = d_in[3];
  const void* Wq    = d_in[4];
  const void* Wk    = d_in[5];
  const void* Wv    = d_in[6];
  const void* We    = d_in[7];
  const void* Ws    = d_in[8];

  // workspace layout (float units) — total ~48.4 MB (round-3/4 proven-safe)
  float* base   = (float*)d_ws;
  int*   flag   = (int*)base;                       // 16
  float* ee     = base + 16;                        // 1024 -> 1040
  int*   rowptr = (int*)(base + 1040);              // 50001 -> pad 50004
  int*   cursor = (int*)(base + 51044);             // 50000 (hist -> cursor)
  int*   bsum   = (int*)(base + 101044);            // 196 -> pad 524
  int*   srcet  = (int*)(base + 101568);            // NE -> 901568
  int*   dstp   = (int*)(base + 901568);            // NE -> 1701568
  int*   setp   = (int*)(base + 1701568);           // NE -> 2501568
  unsigned short* qb  = (unsigned short*)(base + 2501568);  // NN*HC bf16 (3.2M fl)
  unsigned*       kvb = (unsigned*)(base + 5701568);        // NN*HC uint (6.4M fl)
  // end: 12101568 floats = 48.41 MB

  hipMemsetAsync(cursor, 0, NN * sizeof(int), stream);   // hist zero (capture-safe)
  k_prep  <<<HBLK + 1, 256, 0, stream>>>((const int*)eidx, etype,
                                         (const unsigned*)x, emb, We,
                                         flag, cursor, ee, dstp, setp);
  k_scan1 <<<NBLK, 256, 0, stream>>>(cursor, bsum);
  k_scan13<<<NBLK, 256, 0, stream>>>(cursor, bsum, rowptr, cursor);
  k_fused <<<2 * QBLK + HBLK, 256, 0, stream>>>((const unsigned*)x, Wq, Wk, Wv, Ws,
                                                qb, kvb, d_out,
                                                dstp, setp, cursor, srcet);
  k_gather<<<NN / 4, 256, 0, stream>>>(rowptr, srcet, qb, kvb, ee, flag, d_out);
}

// Round 14
// 240.219 us; speedup vs baseline: 1.2674x; 1.0883x over previous
//
#include <hip/hip_runtime.h>
#include <hip/hip_bf16.h>

// Problem constants (from reference):
#define NN 50000   // nodes
#define FF 128     // in channels
#define NH 4       // heads
#define CH 32      // channels/head
#define HC 128     // NH*CH
#define NE 800000  // edges
#define NR 8       // relations
#define DEDIM 64   // edge emb dim
#define NBLK 196   // ceil(NN/256)
#define HBLK 3125  // NE/256
#define QBLK 250   // M-chunk blocks per group in qkvs
#define MTILES 3125 // NN/16

typedef __hip_bfloat16 bf16;
typedef __attribute__((ext_vector_type(8))) short short8;   // 8 x bf16 (4 VGPR)
typedef __attribute__((ext_vector_type(4))) float f32x4;

// ---- helpers ----------------------------------------------------------------
__device__ __forceinline__ float bflo(unsigned u) { return __uint_as_float(u << 16); }
__device__ __forceinline__ float bfhi(unsigned u) { return __uint_as_float(u & 0xFFFF0000u); }

__device__ __forceinline__ unsigned short f2bf(float f) {
  unsigned u = __float_as_uint(f);
  unsigned r = (u + 0x7FFFu + ((u >> 16) & 1u)) >> 16;  // round-nearest-even
  return (unsigned short)r;
}
__device__ __forceinline__ unsigned pack2bf(float lo, float hi) {
  return (unsigned)f2bf(lo) | ((unsigned)f2bf(hi) << 16);
}

template <int ISBF>
__device__ __forceinline__ float ldf(const void* p, size_t i) {
  if (ISBF) return __bfloat162float(((const bf16*)p)[i]);
  return ((const float*)p)[i];
}

__device__ __forceinline__ int idx_at(const void* p, long long i, int is64) {
  if (is64) { long long v = ((const long long*)p)[i]; return (int)v; }
  return ((const int*)p)[i];
}

// ---- MFMA projection pieces (round-8 form) ----------------------------------
#define WT_STRIDE 136   // bf16 elems; 272 B rows: 16B-aligned, 2-way max bank alias

template <int ISBF>
__device__ __forceinline__ void stage_w(const void* __restrict__ W,
                                        unsigned short* __restrict__ wt) {
  for (int i = threadIdx.x; i < FF * HC; i += 256) {
    int k = i >> 7, n = i & 127;
    wt[n * WT_STRIDE + k] = ISBF ? ((const unsigned short*)W)[i]
                                 : f2bf(((const float*)W)[i]);
  }
}

__device__ __forceinline__ void hoist_b(const unsigned short* __restrict__ wt,
                                        int wv, int quad, int lr,
                                        short8 bf[2][4]) {
#pragma unroll
  for (int t = 0; t < 2; ++t) {
    int ncol = wv * 32 + t * 16 + lr;
#pragma unroll
    for (int kb = 0; kb < 4; ++kb)
      bf[t][kb] = *(const short8*)&wt[ncol * WT_STRIDE + kb * 32 + quad * 8];
  }
}

template <int ISBF>
__device__ __forceinline__ void qkvs_body(const void* __restrict__ x,
    const void* __restrict__ W0, const void* __restrict__ W1, int grp, int mc,
    unsigned short* __restrict__ qb, unsigned* __restrict__ kvb,
    void* __restrict__ out, unsigned short* wt) {
  const int lane = threadIdx.x & 63;
  const int wv   = threadIdx.x >> 6;
  const int quad = lane >> 4;
  const int lr   = lane & 15;
  short8 bf0[2][4], bf1[2][4];
  stage_w<ISBF>(W0, wt);
  __syncthreads();
  hoist_b(wt, wv, quad, lr, bf0);
  __syncthreads();           // all reads of W0 done before overwrite
  stage_w<ISBF>(W1, wt);
  __syncthreads();
  hoist_b(wt, wv, quad, lr, bf1);
  const unsigned short* xu = (const unsigned short*)x;
  const float* xf = (const float*)x;
  for (int mt = mc; mt < MTILES; mt += QBLK) {
    int m0 = mt * 16;
    short8 af[4];
#pragma unroll
    for (int kb = 0; kb < 4; ++kb) {
      size_t off = (size_t)(m0 + lr) * FF + kb * 32 + quad * 8;
      if (ISBF) {
        af[kb] = *(const short8*)(xu + off);
      } else {
        float4 fa = *(const float4*)(xf + off);
        float4 fb = *(const float4*)(xf + off + 4);
        short8 a;
        a[0] = (short)f2bf(fa.x); a[1] = (short)f2bf(fa.y);
        a[2] = (short)f2bf(fa.z); a[3] = (short)f2bf(fa.w);
        a[4] = (short)f2bf(fb.x); a[5] = (short)f2bf(fb.y);
        a[6] = (short)f2bf(fb.z); a[7] = (short)f2bf(fb.w);
        af[kb] = a;
      }
    }
    f32x4 a00 = {0.f, 0.f, 0.f, 0.f}, a01 = {0.f, 0.f, 0.f, 0.f};
    f32x4 a10 = {0.f, 0.f, 0.f, 0.f}, a11 = {0.f, 0.f, 0.f, 0.f};
#pragma unroll
    for (int kb = 0; kb < 4; ++kb) {
      a00 = __builtin_amdgcn_mfma_f32_16x16x32_bf16(af[kb], bf0[0][kb], a00, 0, 0, 0);
      a01 = __builtin_amdgcn_mfma_f32_16x16x32_bf16(af[kb], bf0[1][kb], a01, 0, 0, 0);
      a10 = __builtin_amdgcn_mfma_f32_16x16x32_bf16(af[kb], bf1[0][kb], a10, 0, 0, 0);
      a11 = __builtin_amdgcn_mfma_f32_16x16x32_bf16(af[kb], bf1[1][kb], a11, 0, 0, 0);
    }
#pragma unroll
    for (int t = 0; t < 2; ++t) {
      const f32x4 v0 = t ? a01 : a00;   // mat0: q or k
      const f32x4 v1 = t ? a11 : a10;   // mat1: skip or v
      int col = wv * 32 + t * 16 + lr;
#pragma unroll
      for (int r = 0; r < 4; ++r) {
        size_t oi = (size_t)(m0 + quad * 4 + r) * HC + col;
        if (grp == 0) {
          qb[oi] = f2bf(v0[r]);
          if (ISBF) ((unsigned short*)out)[oi] = f2bf(v1[r]);
          else      ((float*)out)[oi] = v1[r];
        } else {
          kvb[oi] = pack2bf(v0[r], v1[r]);   // k low16, v high16
        }
      }
    }
  }
}

// ---- fusedA: qkvs grp0 (q+skip, blocks 0..QBLK-1, dispatched first)
//              + edge prep (hist/rank/drk/setp) + flags/ee (last block) -------
// hist pre-zeroed via hipMemsetAsync. rank stored with dst in UNSIGNED word:
// drk = (unsigned)dst<<16 | rank (NN < 2^16; in-degree ~Poisson(16) << 2^16).
// NOTE round-13 crash: dst>=32768 set the sign bit of a signed int and the
// arithmetic >>16 produced negative indices -> wild writes. Unsigned fixes it.
__global__ __launch_bounds__(256) void k_fusedA(const unsigned* __restrict__ xw,
    const int* __restrict__ eidx32, const void* __restrict__ etype,
    const void* __restrict__ emb, const void* __restrict__ We,
    const void* __restrict__ Wq, const void* __restrict__ Ws,
    int* __restrict__ flag, int* __restrict__ hist, float* __restrict__ ee,
    unsigned* __restrict__ drk, int* __restrict__ setp,
    unsigned short* __restrict__ qb, void* __restrict__ out) {
  __shared__ unsigned short wt[HC * WT_STRIDE];   // ~34 KB (qkvs blocks only)
  if (blockIdx.x < QBLK) {
    // wave-local bf16 detection: 64 exponent samples of x's low halves
    unsigned ex = (xw[threadIdx.x & 63] >> 7) & 0xFFu;
    unsigned long long bb = __ballot(ex < 90u || ex > 140u);
    int isbf = (bb == 0ULL);
    if (isbf) qkvs_body<1>(xw, Wq, Ws, 0, blockIdx.x, qb, nullptr, out, wt);
    else      qkvs_body<0>(xw, Wq, Ws, 0, blockIdx.x, qb, nullptr, out, wt);
    return;
  }
  if (blockIdx.x < QBLK + HBLK) {
    // edge prep: wave-local int64 detection (64 distinct hi-word samples)
    unsigned long long b = __ballot(eidx32[2 * (threadIdx.x & 63) + 1] != 0);
    int is64 = (b == 0ULL);
    int e = (blockIdx.x - QBLK) * 256 + threadIdx.x;   // < NE (HBLK*256 == NE)
    int src = idx_at(eidx32, e, is64);
    int dst = idx_at(eidx32, (long long)NE + e, is64);
    int et  = idx_at(etype, e, is64);
    src = min(max(src, 0), NN - 1);
    dst = min(max(dst, 0), NN - 1);
    et  = min(max(et, 0), NR - 1);
    int rank = atomicAdd(&hist[dst], 1);
    drk[e]  = ((unsigned)dst << 16) | ((unsigned)rank & 0xFFFFu);
    setp[e] = (src << 3) | et;
    return;
  }
  // last block: flags + ee
  float* es = (float*)wt;   // alias (this block doesn't run qkvs)
  __shared__ int nzIdx, badBf;
  if (threadIdx.x == 0) { nzIdx = 0; badBf = 0; }
  __syncthreads();
  if (threadIdx.x < 128) {
    if (eidx32[2 * threadIdx.x + 1] != 0) atomicAdd(&nzIdx, 1);
    unsigned e = (xw[threadIdx.x] >> 7) & 0xFFu;
    if (e < 90u || e > 140u) atomicAdd(&badBf, 1);
  }
  __syncthreads();
  const int isbf = (badBf == 0);
  if (threadIdx.x == 0) { flag[0] = (nzIdx == 0); flag[1] = isbf; }
  for (int i = threadIdx.x; i < NR * DEDIM; i += 256)
    es[i] = isbf ? ldf<1>(emb, i) : ldf<0>(emb, i);
  __syncthreads();
  for (int o = threadIdx.x; o < NR * HC; o += 256) {
    int r = o >> 7, j = o & 127;
    float acc = 0.f;
    if (isbf) { for (int d = 0; d < DEDIM; ++d) acc += es[r * DEDIM + d] * ldf<1>(We, d * HC + j); }
    else      { for (int d = 0; d < DEDIM; ++d) acc += es[r * DEDIM + d] * ldf<0>(We, d * HC + j); }
    ee[o] = acc;
  }
}

// ---- scan: block sums (scan1), then per-block scan with inline top scan ------
__global__ __launch_bounds__(256) void k_scan1(const int* __restrict__ hist,
                                               int* __restrict__ bsum) {
  __shared__ int red[4];
  int i = blockIdx.x * 256 + threadIdx.x;
  int v = (i < NN) ? hist[i] : 0;
#pragma unroll
  for (int m = 1; m < 64; m <<= 1) v += __shfl_xor(v, m);
  if ((threadIdx.x & 63) == 0) red[threadIdx.x >> 6] = v;
  __syncthreads();
  if (threadIdx.x == 0) bsum[blockIdx.x] = red[0] + red[1] + red[2] + red[3];
}

__global__ __launch_bounds__(256) void k_scan13(const int* __restrict__ hist,
    const int* __restrict__ bsum, int* __restrict__ rowptr) {
  __shared__ int s[256];
  int t = threadIdx.x;
  int bv = (t < NBLK) ? bsum[t] : 0;
  s[t] = bv;
  __syncthreads();
  for (int off = 1; off < 256; off <<= 1) {
    int u = (t >= off) ? s[t - off] : 0;
    __syncthreads();
    s[t] += u;
    __syncthreads();
  }
  int bexc = (blockIdx.x == 0) ? 0 : s[blockIdx.x - 1];  // uniform
  __syncthreads();
  int i = blockIdx.x * 256 + t;
  int v = (i < NN) ? hist[i] : 0;
  s[t] = v;
  __syncthreads();
  for (int off = 1; off < 256; off <<= 1) {
    int u = (t >= off) ? s[t - off] : 0;
    __syncthreads();
    s[t] += u;
    __syncthreads();
  }
  int excl = bexc + s[t] - v;
  if (i < NN) rowptr[i] = excl;
  if (i == 0) rowptr[NN] = NE;   // all edges binned (dst clamped)
}

// ---- fusedB: qkvs grp1 (k+v, blocks 0..QBLK-1, dispatched first)
//              + atomic-free scatter (rank precomputed in prep) ---------------
__global__ __launch_bounds__(256) void k_fusedB(const unsigned* __restrict__ xw,
    const void* __restrict__ Wk, const void* __restrict__ Wv,
    unsigned* __restrict__ kvb,
    const unsigned* __restrict__ drk, const int* __restrict__ setp,
    const int* __restrict__ rowptr, int* __restrict__ srcet) {
  __shared__ unsigned short wt[HC * WT_STRIDE];   // ~34 KB (qkvs blocks only)
  if (blockIdx.x < QBLK) {
    unsigned ex = (xw[threadIdx.x & 63] >> 7) & 0xFFu;
    unsigned long long bb = __ballot(ex < 90u || ex > 140u);
    int isbf = (bb == 0ULL);
    if (isbf) qkvs_body<1>(xw, Wk, Wv, 1, blockIdx.x, nullptr, kvb, nullptr, wt);
    else      qkvs_body<0>(xw, Wk, Wv, 1, blockIdx.x, nullptr, kvb, nullptr, wt);
    return;
  }
  // scatter: srcet[rowptr[dst] + rank] = setp[e]  (no atomics; logical shifts)
  int e = (blockIdx.x - QBLK) * 256 + threadIdx.x;   // HBLK*256 == NE
  unsigned d = drk[e];
  int pos = rowptr[d >> 16] + (int)(d & 0xFFFFu);
  pos = min(max(pos, 0), NE - 1);   // crash insurance (no-op for valid input)
  srcet[pos] = setp[e];
}

// ---- fused attention+gather: half-wave per edge, 4 channels/lane ------------
// lane l: t = l>>5 (edge slot), w = l&31, head = w>>3, j0 = 32*head + 4*(w&7)
__global__ __launch_bounds__(256) void k_gather(const int* __restrict__ rowptr,
    const int* __restrict__ srcet, const unsigned short* __restrict__ qb,
    const unsigned* __restrict__ kvb, const float* __restrict__ ee,
    const int* __restrict__ flag, void* __restrict__ out) {
  int n = blockIdx.x * 4 + (threadIdx.x >> 6);   // wave-uniform node
  int l = threadIdx.x & 63;
  int t = l >> 5;
  int w = l & 31;
  int j0 = ((w >> 3) << 5) + ((w & 7) << 2);     // 4-channel base
  int beg = __builtin_amdgcn_readfirstlane(rowptr[n]);
  int end = __builtin_amdgcn_readfirstlane(rowptr[n + 1]);
  uint2 qw = *(const uint2*)(qb + (size_t)n * HC + j0);
  float q0 = bflo(qw.x), q1 = bfhi(qw.x), q2 = bflo(qw.y), q3 = bfhi(qw.y);
  const float sc = 0.17677669529663687f;  // 1/sqrt(32)
  float dn = 0.f, a0 = 0.f, a1 = 0.f, a2 = 0.f, a3 = 0.f;
  int p = beg;
  // main: 4 pairs (8 edges) per iteration, unmasked
  for (; p + 8 <= end; p += 8) {
    int se[4]; uint4 kv[4]; float4 ev[4];
#pragma unroll
    for (int u = 0; u < 4; ++u) se[u] = srcet[p + 2 * u + t];
#pragma unroll
    for (int u = 0; u < 4; ++u)
      kv[u] = *(const uint4*)(kvb + (size_t)(se[u] >> 3) * HC + j0);
#pragma unroll
    for (int u = 0; u < 4; ++u)
      ev[u] = *(const float4*)(ee + ((se[u] & 7) << 7) + j0);
#pragma unroll
    for (int u = 0; u < 4; ++u) {
      float pp = q0 * (bflo(kv[u].x) + ev[u].x) + q1 * (bflo(kv[u].y) + ev[u].y)
               + q2 * (bflo(kv[u].z) + ev[u].z) + q3 * (bflo(kv[u].w) + ev[u].w);
      pp += __shfl_xor(pp, 1);
      pp += __shfl_xor(pp, 2);
      pp += __shfl_xor(pp, 4);
      float xx = __expf(pp * sc);
      dn += xx;
      a0 += (bfhi(kv[u].x) + ev[u].x) * xx;
      a1 += (bfhi(kv[u].y) + ev[u].y) * xx;
      a2 += (bfhi(kv[u].z) + ev[u].z) * xx;
      a3 += (bfhi(kv[u].w) + ev[u].w) * xx;
    }
  }
  // epilogue: one masked 4-pair iteration covers the <8 remaining edges
  if (p < end) {
    int se[4]; bool ok[4]; uint4 kv[4]; float4 ev[4];
#pragma unroll
    for (int u = 0; u < 4; ++u) {
      int pe = p + 2 * u + t;
      ok[u] = pe < end;
      se[u] = srcet[ok[u] ? pe : beg];
    }
#pragma unroll
    for (int u = 0; u < 4; ++u)
      kv[u] = *(const uint4*)(kvb + (size_t)(se[u] >> 3) * HC + j0);
#pragma unroll
    for (int u = 0; u < 4; ++u)
      ev[u] = *(const float4*)(ee + ((se[u] & 7) << 7) + j0);
#pragma unroll
    for (int u = 0; u < 4; ++u) {
      float pp = q0 * (bflo(kv[u].x) + ev[u].x) + q1 * (bflo(kv[u].y) + ev[u].y)
               + q2 * (bflo(kv[u].z) + ev[u].z) + q3 * (bflo(kv[u].w) + ev[u].w);
      pp += __shfl_xor(pp, 1);
      pp += __shfl_xor(pp, 2);
      pp += __shfl_xor(pp, 4);
      float xx = ok[u] ? __expf(pp * sc) : 0.f;
      dn += xx;
      a0 += (bfhi(kv[u].x) + ev[u].x) * xx;
      a1 += (bfhi(kv[u].y) + ev[u].y) * xx;
      a2 += (bfhi(kv[u].z) + ev[u].z) * xx;
      a3 += (bfhi(kv[u].w) + ev[u].w) * xx;
    }
  }
  // combine the two half-waves (linear in numerator and denominator)
  dn += __shfl_xor(dn, 32);
  a0 += __shfl_xor(a0, 32);
  a1 += __shfl_xor(a1, 32);
  a2 += __shfl_xor(a2, 32);
  a3 += __shfl_xor(a3, 32);
  if (t == 0) {
    float inv = 1.f / (dn + 1e-16f);
    size_t oi = (size_t)n * HC + j0;
    if (flag[1]) {  // skip pre-stored dtype-matched in d_out; same-thread RAW, safe
      uint2 sk = *(const uint2*)((const unsigned short*)out + oi);
      uint2 o;
      o.x = pack2bf(a0 * inv + bflo(sk.x), a1 * inv + bfhi(sk.x));
      o.y = pack2bf(a2 * inv + bflo(sk.y), a3 * inv + bfhi(sk.y));
      *(uint2*)((unsigned short*)out + oi) = o;
    } else {
      float4 sk = *(const float4*)((const float*)out + oi);
      float4 o = make_float4(a0 * inv + sk.x, a1 * inv + sk.y,
                             a2 * inv + sk.z, a3 * inv + sk.w);
      *(float4*)((float*)out + oi) = o;
    }
  }
}

// ---- launch -----------------------------------------------------------------
extern "C" void kernel_launch(void* const* d_in, const int* in_sizes, int n_in,
                              void* d_out, int out_size, void* d_ws, size_t ws_size,
                              hipStream_t stream) {
  const void* x     = d_in[0];
  const void* eidx  = d_in[1];   // [2,E]: first E = src, next E = dst
  const void* etype = d_in[2];
  const void* emb   = d_in[3];
  const void* Wq    = d_in[4];
  const void* Wk    = d_in[5];
  const void* Wv    = d_in[6];
  const void* We    = d_in[7];
  const void* Ws    = d_in[8];

  // workspace layout (float units) — total ~48.4 MB (round-3/4 proven-safe)
  float* base   = (float*)d_ws;
  int*   flag   = (int*)base;                       // 16
  float* ee     = base + 16;                        // 1024 -> 1040
  int*   rowptr = (int*)(base + 1040);              // 50001 -> pad 50004
  int*   hist   = (int*)(base + 51044);             // 50000
  int*   bsum   = (int*)(base + 101044);            // 196 -> pad 524
  int*   srcet  = (int*)(base + 101568);            // NE -> 901568
  unsigned* drk = (unsigned*)(base + 901568);       // NE (dst<<16|rank) -> 1701568
  int*   setp   = (int*)(base + 1701568);           // NE -> 2501568
  unsigned short* qb  = (unsigned short*)(base + 2501568);  // NN*HC bf16 (3.2M fl)
  unsigned*       kvb = (unsigned*)(base + 5701568);        // NN*HC uint (6.4M fl)
  // end: 12101568 floats = 48.41 MB

  hipMemsetAsync(hist, 0, NN * sizeof(int), stream);   // hist zero (capture-safe)
  k_fusedA<<<QBLK + HBLK + 1, 256, 0, stream>>>((const unsigned*)x,
                                                (const int*)eidx, etype, emb, We,
                                                Wq, Ws, flag, hist, ee,
                                                drk, setp, qb, d_out);
  k_scan1 <<<NBLK, 256, 0, stream>>>(hist, bsum);
  k_scan13<<<NBLK, 256, 0, stream>>>(hist, bsum, rowptr);
  k_fusedB<<<QBLK + HBLK, 256, 0, stream>>>((const unsigned*)x, Wk, Wv, kvb,
                                            drk, setp, rowptr, srcet);
  k_gather<<<NN / 4, 256, 0, stream>>>(rowptr, srcet, qb, kvb, ee, flag, d_out);
}